// Round 3
// baseline (17775.797 us; speedup 1.0000x reference)
//
#include <hip/hip_runtime.h>
#include <math.h>

#define N_ROWS 12288
#define DIM 256
#define K_TOP 32

// ---------------- Kernel 1: L2 row normalize ----------------
__global__ __launch_bounds__(256) void normalize_rows(const float* __restrict__ x,
                                                      float* __restrict__ xn) {
    int row = blockIdx.x;
    int t = threadIdx.x;
    float v = x[(size_t)row * DIM + t];
    float sq = v * v;
    #pragma unroll
    for (int off = 32; off > 0; off >>= 1)
        sq += __shfl_down(sq, off, 64);
    __shared__ float ws[4];
    if ((t & 63) == 0) ws[t >> 6] = sq;
    __syncthreads();
    float total = ws[0] + ws[1] + ws[2] + ws[3];
    float norm = fmaxf(sqrtf(total), 1e-12f);
    xn[(size_t)row * DIM + t] = v / norm;
}

// ---------------- Kernel 2: symmetric adj = xn @ xn^T (fp32) ----------------
// Exact lower-triangle grid (4656 blocks). Broadcast-friendly fragment map:
//   thread rows  = {ty*4+0..3, 64+ty*4+0..3}   (a-reads broadcast across wave)
//   thread cols  = {tx*4+0..3, 64+tx*4+0..3}   (b-reads 16B-stride, 2-way = free)
// LDS padded to 132 (staging writes 4-way -> 2-way). Transpose scratch aliased
// onto the As/Bs buffers (total LDS 33 KB -> 4 blocks/CU by LDS).
#define BM 128
#define BN 128
#define BK 16
#define BMP 132
#define TRP 140
#define NT (N_ROWS / BM)   // 96

#define AS(buf, k, r) smem[(buf)*(2*BK*BMP) + (k)*BMP + (r)]
#define BS(buf, k, r) smem[(buf)*(2*BK*BMP) + (BK*BMP) + (k)*BMP + (r)]
#define TRS(r, c)     smem[(r)*TRP + (c)]

__global__ __launch_bounds__(256, 3) void gemm_sym(const float* __restrict__ A,
                                                   float* __restrict__ C) {
    __shared__ float smem[2 * 2 * BK * BMP];   // 33792 B

    // triangular decode: block L -> (bi, bj), bj <= bi
    int L = blockIdx.x;
    int bi = (int)((sqrtf(8.0f * (float)L + 1.0f) - 1.0f) * 0.5f);
    while ((bi + 1) * (bi + 2) / 2 <= L) ++bi;
    while (bi * (bi + 1) / 2 > L) --bi;
    int bj = L - bi * (bi + 1) / 2;

    int tid = threadIdx.x;
    int tx = tid & 15, ty = tid >> 4;
    int tx4 = tx * 4, ty4 = ty * 4;
    int r0 = tid >> 2, q0 = tid & 3;      // staging: rows r0, r0+64; float4 quad q0
    const float* Abase = A + (size_t)(bi * BM) * DIM;
    const float* Bbase = A + (size_t)(bj * BN) * DIM;
    float acc[8][8] = {};
    float4 pa0, pa1, pb0, pb1;

    pa0 = *(const float4*)(Abase + (size_t)r0 * DIM + q0 * 4);
    pa1 = *(const float4*)(Abase + (size_t)(r0 + 64) * DIM + q0 * 4);
    pb0 = *(const float4*)(Bbase + (size_t)r0 * DIM + q0 * 4);
    pb1 = *(const float4*)(Bbase + (size_t)(r0 + 64) * DIM + q0 * 4);
    {
        const float* a0 = (const float*)&pa0; const float* a1 = (const float*)&pa1;
        const float* b0 = (const float*)&pb0; const float* b1 = (const float*)&pb1;
        #pragma unroll
        for (int c = 0; c < 4; ++c) {
            AS(0, q0 * 4 + c, r0) = a0[c];  AS(0, q0 * 4 + c, r0 + 64) = a1[c];
            BS(0, q0 * 4 + c, r0) = b0[c];  BS(0, q0 * 4 + c, r0 + 64) = b1[c];
        }
    }
    __syncthreads();

    int p = 0;
    #pragma unroll 1
    for (int it = 0; it < DIM / BK; ++it) {
        bool has_next = (it + 1) < (DIM / BK);
        if (has_next) {
            int k0 = (it + 1) * BK;
            pa0 = *(const float4*)(Abase + (size_t)r0 * DIM + k0 + q0 * 4);
            pa1 = *(const float4*)(Abase + (size_t)(r0 + 64) * DIM + k0 + q0 * 4);
            pb0 = *(const float4*)(Bbase + (size_t)r0 * DIM + k0 + q0 * 4);
            pb1 = *(const float4*)(Bbase + (size_t)(r0 + 64) * DIM + k0 + q0 * 4);
        }
        #pragma unroll
        for (int kk = 0; kk < BK; ++kk) {
            float a[8], b[8];
            *(float4*)&a[0] = *(const float4*)&AS(p, kk, ty4);
            *(float4*)&a[4] = *(const float4*)&AS(p, kk, ty4 + 64);
            *(float4*)&b[0] = *(const float4*)&BS(p, kk, tx4);
            *(float4*)&b[4] = *(const float4*)&BS(p, kk, tx4 + 64);
            #pragma unroll
            for (int i = 0; i < 8; ++i)
                #pragma unroll
                for (int j = 0; j < 8; ++j)
                    acc[i][j] = fmaf(a[i], b[j], acc[i][j]);
        }
        if (has_next) {
            int np = p ^ 1;
            const float* a0 = (const float*)&pa0; const float* a1 = (const float*)&pa1;
            const float* b0 = (const float*)&pb0; const float* b1 = (const float*)&pb1;
            #pragma unroll
            for (int c = 0; c < 4; ++c) {
                AS(np, q0 * 4 + c, r0) = a0[c];  AS(np, q0 * 4 + c, r0 + 64) = a1[c];
                BS(np, q0 * 4 + c, r0) = b0[c];  BS(np, q0 * 4 + c, r0 + 64) = b1[c];
            }
        }
        __syncthreads();
        p ^= 1;
    }

    // direct tile write: rows bi*BM + {ty4+i03, 64+ty4+i03}, cols bj*BN + {tx4.., 64+tx4..}
    #pragma unroll
    for (int i = 0; i < 8; ++i) {
        int rl = ty4 + (i & 3) + (i >> 2) * 64;
        float* outp = C + (size_t)(bi * BM + rl) * N_ROWS + bj * BN;
        *(float4*)(outp + tx4)      = *(float4*)&acc[i][0];
        *(float4*)(outp + 64 + tx4) = *(float4*)&acc[i][4];
    }
    if (bi == bj) return;

    // mirror tile via aliased LDS transpose, 32 original-columns per chunk
    #pragma unroll 1
    for (int c4 = 0; c4 < 4; ++c4) {
        __syncthreads();
        if ((tx >> 3) == (c4 & 1)) {
            int jh = c4 >> 1;
            #pragma unroll
            for (int j03 = 0; j03 < 4; ++j03)
                #pragma unroll
                for (int i = 0; i < 8; ++i) {
                    int rl = ty4 + (i & 3) + (i >> 2) * 64;
                    TRS((tx & 7) * 4 + j03, rl) = acc[i][jh * 4 + j03];
                }
        }
        __syncthreads();
        int rr = tid >> 3;            // 0..31
        int cc = (tid & 7) * 16;      // 0..112
        float* dst = C + (size_t)(bj * BN + c4 * 32 + rr) * N_ROWS + bi * BM + cc;
        *(float4*)(dst + 0)  = *(const float4*)&TRS(rr, cc + 0);
        *(float4*)(dst + 4)  = *(const float4*)&TRS(rr, cc + 4);
        *(float4*)(dst + 8)  = *(const float4*)&TRS(rr, cc + 8);
        *(float4*)(dst + 12) = *(const float4*)&TRS(rr, cc + 12);
    }
}

// ---------------- Kernel 3: exact per-row top-K mask (streamed) ----------------
__device__ __forceinline__ unsigned int f2key(float f) {
    unsigned int u = __float_as_uint(f);
    return (u & 0x80000000u) ? ~u : (u | 0x80000000u);
}
__device__ __forceinline__ unsigned long long composite(float v, int j) {
    return ((unsigned long long)f2key(v) << 32) | (unsigned int)(N_ROWS - j);
}
__device__ __forceinline__ unsigned long long shfl_xor_u64(unsigned long long x, int m) {
    unsigned int lo = (unsigned int)x, hi = (unsigned int)(x >> 32);
    lo = __shfl_xor(lo, m, 64);
    hi = __shfl_xor(hi, m, 64);
    return ((unsigned long long)hi << 32) | lo;
}
__device__ __forceinline__ unsigned long long shfl_down_u64(unsigned long long x, int off) {
    unsigned int lo = (unsigned int)x, hi = (unsigned int)(x >> 32);
    lo = __shfl_down(lo, off, 64);
    hi = __shfl_down(hi, off, 64);
    return ((unsigned long long)hi << 32) | lo;
}

#define CAND_CAP 2048

__global__ __launch_bounds__(256, 4) void topk_mask(float* __restrict__ adj) {
    __shared__ float cval[CAND_CAP];
    __shared__ int cidx[CAND_CAP];
    __shared__ int count;
    __shared__ unsigned long long bt[256];
    __shared__ unsigned long long red[4];
    __shared__ unsigned long long bc64;

    int row = blockIdx.x;
    int t = threadIdx.x;
    float* rp = adj + (size_t)row * N_ROWS;
    const float4* rp4 = (const float4*)rp;

    // candidate compaction, streaming from global (no register residency)
    float T = 0.145f;
    int M;
    #pragma unroll 1
    while (true) {
        if (t == 0) count = 0;
        __syncthreads();
        #pragma unroll 1
        for (int c = 0; c < 12; ++c) {
            float4 w = rp4[c * 256 + t];
            int jb = 4 * (c * 256 + t);
            if (w.x > T) { int p = atomicAdd(&count, 1); if (p < CAND_CAP) { cval[p] = w.x; cidx[p] = jb + 0; } }
            if (w.y > T) { int p = atomicAdd(&count, 1); if (p < CAND_CAP) { cval[p] = w.y; cidx[p] = jb + 1; } }
            if (w.z > T) { int p = atomicAdd(&count, 1); if (p < CAND_CAP) { cval[p] = w.z; cidx[p] = jb + 2; } }
            if (w.w > T) { int p = atomicAdd(&count, 1); if (p < CAND_CAP) { cval[p] = w.w; cidx[p] = jb + 3; } }
        }
        __syncthreads();
        M = count < CAND_CAP ? count : CAND_CAP;
        if (M >= K_TOP) break;
        T -= 0.03f;
        __syncthreads();
    }

    unsigned long long cutoff;
    if (M <= 256) {
        // bitonic-256 descending sort of composites; cutoff = element [31]
        unsigned long long v = (t < M) ? composite(cval[t], cidx[t]) : 0ULL;
        #pragma unroll 1
        for (int k = 2; k <= 256; k <<= 1) {
            #pragma unroll 1
            for (int j = k >> 1; j >= 1; j >>= 1) {
                unsigned long long other;
                if (j >= 64) {
                    bt[t] = v;
                    __syncthreads();
                    other = bt[t ^ j];
                    __syncthreads();
                } else {
                    other = shfl_xor_u64(v, j);
                }
                bool down = ((t & k) == 0);
                bool lower = ((t & j) == 0);
                bool take_max = (down == lower);
                bool omax = (other > v);
                v = (take_max == omax) ? other : v;
            }
        }
        if (t == 31) bc64 = v;
        __syncthreads();
        cutoff = bc64;
    } else {
        // fallback: K rounds of block argmax (rare)
        cutoff = 0;
        #pragma unroll 1
        for (int r2 = 0; r2 < K_TOP; ++r2) {
            unsigned long long best = 0;
            for (int p2 = t; p2 < M; p2 += 256) {
                int id = cidx[p2];
                if (id >= 0) {
                    unsigned long long comp = composite(cval[p2], id);
                    if (comp > best) best = comp;
                }
            }
            #pragma unroll
            for (int off = 32; off > 0; off >>= 1) {
                unsigned long long o = shfl_down_u64(best, off);
                if (o > best) best = o;
            }
            if ((t & 63) == 0) red[t >> 6] = best;
            __syncthreads();
            unsigned long long win = red[0];
            if (red[1] > win) win = red[1];
            if (red[2] > win) win = red[2];
            if (red[3] > win) win = red[3];
            cutoff = win;
            int jwin = N_ROWS - (int)(win & 0xFFFFFFFFu);
            __syncthreads();
            for (int p2 = t; p2 < M; p2 += 256)
                if (cidx[p2] == jwin) cidx[p2] = -1;
            __syncthreads();
        }
    }

    // masked rewrite, streaming (row is L2/L3-warm from compaction pass)
    #pragma unroll 1
    for (int c = 0; c < 12; ++c) {
        float4 w = rp4[c * 256 + t];
        int jb = 4 * (c * 256 + t);
        float4 o;
        o.x = (composite(w.x, jb + 0) >= cutoff) ? w.x : 0.0f;
        o.y = (composite(w.y, jb + 1) >= cutoff) ? w.y : 0.0f;
        o.z = (composite(w.z, jb + 2) >= cutoff) ? w.z : 0.0f;
        o.w = (composite(w.w, jb + 3) >= cutoff) ? w.w : 0.0f;
        ((float4*)rp)[c * 256 + t] = o;
    }
}

extern "C" void kernel_launch(void* const* d_in, const int* in_sizes, int n_in,
                              void* d_out, int out_size, void* d_ws, size_t ws_size,
                              hipStream_t stream) {
    const float* x = (const float*)d_in[0];
    float* out = (float*)d_out;
    float* xn = (float*)d_ws;   // 12.6 MB scratch

    normalize_rows<<<N_ROWS, 256, 0, stream>>>(x, xn);
    gemm_sym<<<NT * (NT + 1) / 2, 256, 0, stream>>>(xn, out);
    topk_mask<<<N_ROWS, 256, 0, stream>>>(out);
}

// Round 4
// 1516.117 us; speedup vs baseline: 11.7246x; 11.7246x over previous
//
#include <hip/hip_runtime.h>
#include <math.h>

#define N_ROWS 12288
#define DIM 256
#define K_TOP 32

// ---------------- Kernel 1: L2 row normalize ----------------
__global__ __launch_bounds__(256) void normalize_rows(const float* __restrict__ x,
                                                      float* __restrict__ xn) {
    int row = blockIdx.x;
    int t = threadIdx.x;
    float v = x[(size_t)row * DIM + t];
    float sq = v * v;
    #pragma unroll
    for (int off = 32; off > 0; off >>= 1)
        sq += __shfl_down(sq, off, 64);
    __shared__ float ws[4];
    if ((t & 63) == 0) ws[t >> 6] = sq;
    __syncthreads();
    float total = ws[0] + ws[1] + ws[2] + ws[3];
    float norm = fmaxf(sqrtf(total), 1e-12f);
    xn[(size_t)row * DIM + t] = v / norm;
}

// ---------------- Kernel 2: symmetric adj = xn @ xn^T (fp32) ----------------
// Exact lower-triangle grid. Broadcast fragment map (a: 4 addrs/wave,
// b: 16B-stride 2-way = free). LDS padded to 132. NOTE: every access into
// acc[][] must use compile-time indices — runtime indexing demotes the
// array to scratch (Round 3: 27 GB scratch traffic, 15x regression).
#define BM 128
#define BN 128
#define BK 16
#define BMP 132
#define TRP 140
#define NT (N_ROWS / BM)   // 96

#define AS(buf, k, r) smem[(buf)*(2*BK*BMP) + (k)*BMP + (r)]
#define BS(buf, k, r) smem[(buf)*(2*BK*BMP) + (BK*BMP) + (k)*BMP + (r)]
#define TRS(r, c)     smem[(r)*TRP + (c)]

__global__ __launch_bounds__(256) void gemm_sym(const float* __restrict__ A,
                                               float* __restrict__ C) {
    __shared__ float smem[2 * 2 * BK * BMP];   // 33792 B

    // triangular decode: block L -> (bi, bj), bj <= bi
    int L = blockIdx.x;
    int bi = (int)((sqrtf(8.0f * (float)L + 1.0f) - 1.0f) * 0.5f);
    while ((bi + 1) * (bi + 2) / 2 <= L) ++bi;
    while (bi * (bi + 1) / 2 > L) --bi;
    int bj = L - bi * (bi + 1) / 2;

    int tid = threadIdx.x;
    int tx = tid & 15, ty = tid >> 4;
    int tx4 = tx * 4, ty4 = ty * 4;
    int r0 = tid >> 2, q0 = tid & 3;      // staging: rows r0, r0+64; float4 quad q0
    const float* Abase = A + (size_t)(bi * BM) * DIM;
    const float* Bbase = A + (size_t)(bj * BN) * DIM;
    float acc[8][8] = {};
    float4 pa0, pa1, pb0, pb1;

    pa0 = *(const float4*)(Abase + (size_t)r0 * DIM + q0 * 4);
    pa1 = *(const float4*)(Abase + (size_t)(r0 + 64) * DIM + q0 * 4);
    pb0 = *(const float4*)(Bbase + (size_t)r0 * DIM + q0 * 4);
    pb1 = *(const float4*)(Bbase + (size_t)(r0 + 64) * DIM + q0 * 4);
    {
        const float* a0 = (const float*)&pa0; const float* a1 = (const float*)&pa1;
        const float* b0 = (const float*)&pb0; const float* b1 = (const float*)&pb1;
        #pragma unroll
        for (int c = 0; c < 4; ++c) {
            AS(0, q0 * 4 + c, r0) = a0[c];  AS(0, q0 * 4 + c, r0 + 64) = a1[c];
            BS(0, q0 * 4 + c, r0) = b0[c];  BS(0, q0 * 4 + c, r0 + 64) = b1[c];
        }
    }
    __syncthreads();

    int p = 0;
    #pragma unroll 1
    for (int it = 0; it < DIM / BK; ++it) {
        bool has_next = (it + 1) < (DIM / BK);
        if (has_next) {
            int k0 = (it + 1) * BK;
            pa0 = *(const float4*)(Abase + (size_t)r0 * DIM + k0 + q0 * 4);
            pa1 = *(const float4*)(Abase + (size_t)(r0 + 64) * DIM + k0 + q0 * 4);
            pb0 = *(const float4*)(Bbase + (size_t)r0 * DIM + k0 + q0 * 4);
            pb1 = *(const float4*)(Bbase + (size_t)(r0 + 64) * DIM + k0 + q0 * 4);
        }
        #pragma unroll
        for (int kk = 0; kk < BK; ++kk) {
            float a[8], b[8];
            *(float4*)&a[0] = *(const float4*)&AS(p, kk, ty4);
            *(float4*)&a[4] = *(const float4*)&AS(p, kk, ty4 + 64);
            *(float4*)&b[0] = *(const float4*)&BS(p, kk, tx4);
            *(float4*)&b[4] = *(const float4*)&BS(p, kk, tx4 + 64);
            #pragma unroll
            for (int i = 0; i < 8; ++i)
                #pragma unroll
                for (int j = 0; j < 8; ++j)
                    acc[i][j] = fmaf(a[i], b[j], acc[i][j]);
        }
        if (has_next) {
            int np = p ^ 1;
            const float* a0 = (const float*)&pa0; const float* a1 = (const float*)&pa1;
            const float* b0 = (const float*)&pb0; const float* b1 = (const float*)&pb1;
            #pragma unroll
            for (int c = 0; c < 4; ++c) {
                AS(np, q0 * 4 + c, r0) = a0[c];  AS(np, q0 * 4 + c, r0 + 64) = a1[c];
                BS(np, q0 * 4 + c, r0) = b0[c];  BS(np, q0 * 4 + c, r0 + 64) = b1[c];
            }
        }
        __syncthreads();
        p ^= 1;
    }

    // direct tile write: row rl(i) = ty4 + (i&3) + (i>>2)*64, cols tx4.. / 64+tx4..
    #pragma unroll
    for (int i = 0; i < 8; ++i) {
        int rl = ty4 + (i & 3) + (i >> 2) * 64;
        float* outp = C + (size_t)(bi * BM + rl) * N_ROWS + bj * BN;
        *(float4*)(outp + tx4)      = *(float4*)&acc[i][0];
        *(float4*)(outp + 64 + tx4) = *(float4*)&acc[i][4];
    }
    if (bi == bj) return;

    // mirror tile via aliased LDS transpose, FULLY UNROLLED so all acc[][]
    // indices are compile-time (runtime index => scratch demotion!).
    #pragma unroll
    for (int c4 = 0; c4 < 4; ++c4) {
        __syncthreads();
        if ((tx >> 3) == (c4 & 1)) {
            #pragma unroll
            for (int j03 = 0; j03 < 4; ++j03)
                #pragma unroll
                for (int i = 0; i < 8; ++i) {
                    int rl = ty4 + (i & 3) + (i >> 2) * 64;
                    TRS((tx & 7) * 4 + j03, rl) = acc[i][(c4 >> 1) * 4 + j03];
                }
        }
        __syncthreads();
        int rr = tid >> 3;            // 0..31
        int cc = (tid & 7) * 16;      // 0..112
        float* dst = C + (size_t)(bj * BN + c4 * 32 + rr) * N_ROWS + bi * BM + cc;
        *(float4*)(dst + 0)  = *(const float4*)&TRS(rr, cc + 0);
        *(float4*)(dst + 4)  = *(const float4*)&TRS(rr, cc + 4);
        *(float4*)(dst + 8)  = *(const float4*)&TRS(rr, cc + 8);
        *(float4*)(dst + 12) = *(const float4*)&TRS(rr, cc + 12);
    }
}

// ---------------- Kernel 3: exact per-row top-K mask (streamed) ----------------
__device__ __forceinline__ unsigned int f2key(float f) {
    unsigned int u = __float_as_uint(f);
    return (u & 0x80000000u) ? ~u : (u | 0x80000000u);
}
__device__ __forceinline__ unsigned long long composite(float v, int j) {
    return ((unsigned long long)f2key(v) << 32) | (unsigned int)(N_ROWS - j);
}
__device__ __forceinline__ unsigned long long shfl_xor_u64(unsigned long long x, int m) {
    unsigned int lo = (unsigned int)x, hi = (unsigned int)(x >> 32);
    lo = __shfl_xor(lo, m, 64);
    hi = __shfl_xor(hi, m, 64);
    return ((unsigned long long)hi << 32) | lo;
}
__device__ __forceinline__ unsigned long long shfl_down_u64(unsigned long long x, int off) {
    unsigned int lo = (unsigned int)x, hi = (unsigned int)(x >> 32);
    lo = __shfl_down(lo, off, 64);
    hi = __shfl_down(hi, off, 64);
    return ((unsigned long long)hi << 32) | lo;
}

#define CAND_CAP 2048

__global__ __launch_bounds__(256, 4) void topk_mask(float* __restrict__ adj) {
    __shared__ float cval[CAND_CAP];
    __shared__ int cidx[CAND_CAP];
    __shared__ int count;
    __shared__ unsigned long long bt[256];
    __shared__ unsigned long long red[4];
    __shared__ unsigned long long bc64;

    int row = blockIdx.x;
    int t = threadIdx.x;
    float* rp = adj + (size_t)row * N_ROWS;
    const float4* rp4 = (const float4*)rp;

    // candidate compaction, streaming from global
    float T = 0.145f;
    int M;
    #pragma unroll 1
    while (true) {
        if (t == 0) count = 0;
        __syncthreads();
        #pragma unroll 1
        for (int c = 0; c < 12; ++c) {
            float4 w = rp4[c * 256 + t];
            int jb = 4 * (c * 256 + t);
            if (w.x > T) { int p = atomicAdd(&count, 1); if (p < CAND_CAP) { cval[p] = w.x; cidx[p] = jb + 0; } }
            if (w.y > T) { int p = atomicAdd(&count, 1); if (p < CAND_CAP) { cval[p] = w.y; cidx[p] = jb + 1; } }
            if (w.z > T) { int p = atomicAdd(&count, 1); if (p < CAND_CAP) { cval[p] = w.z; cidx[p] = jb + 2; } }
            if (w.w > T) { int p = atomicAdd(&count, 1); if (p < CAND_CAP) { cval[p] = w.w; cidx[p] = jb + 3; } }
        }
        __syncthreads();
        M = count < CAND_CAP ? count : CAND_CAP;
        if (M >= K_TOP) break;
        T -= 0.03f;
        __syncthreads();
    }

    unsigned long long cutoff;
    if (M <= 256) {
        // bitonic-256 descending sort of composites; cutoff = element [31]
        unsigned long long v = (t < M) ? composite(cval[t], cidx[t]) : 0ULL;
        #pragma unroll 1
        for (int k = 2; k <= 256; k <<= 1) {
            #pragma unroll 1
            for (int j = k >> 1; j >= 1; j >>= 1) {
                unsigned long long other;
                if (j >= 64) {
                    bt[t] = v;
                    __syncthreads();
                    other = bt[t ^ j];
                    __syncthreads();
                } else {
                    other = shfl_xor_u64(v, j);
                }
                bool down = ((t & k) == 0);
                bool lower = ((t & j) == 0);
                bool take_max = (down == lower);
                bool omax = (other > v);
                v = (take_max == omax) ? other : v;
            }
        }
        if (t == 31) bc64 = v;
        __syncthreads();
        cutoff = bc64;
    } else {
        // fallback: K rounds of block argmax (rare)
        cutoff = 0;
        #pragma unroll 1
        for (int r2 = 0; r2 < K_TOP; ++r2) {
            unsigned long long best = 0;
            for (int p2 = t; p2 < M; p2 += 256) {
                int id = cidx[p2];
                if (id >= 0) {
                    unsigned long long comp = composite(cval[p2], id);
                    if (comp > best) best = comp;
                }
            }
            #pragma unroll
            for (int off = 32; off > 0; off >>= 1) {
                unsigned long long o = shfl_down_u64(best, off);
                if (o > best) best = o;
            }
            if ((t & 63) == 0) red[t >> 6] = best;
            __syncthreads();
            unsigned long long win = red[0];
            if (red[1] > win) win = red[1];
            if (red[2] > win) win = red[2];
            if (red[3] > win) win = red[3];
            cutoff = win;
            int jwin = N_ROWS - (int)(win & 0xFFFFFFFFu);
            __syncthreads();
            for (int p2 = t; p2 < M; p2 += 256)
                if (cidx[p2] == jwin) cidx[p2] = -1;
            __syncthreads();
        }
    }

    // masked rewrite, streaming (row is L2/L3-warm from compaction pass)
    #pragma unroll 1
    for (int c = 0; c < 12; ++c) {
        float4 w = rp4[c * 256 + t];
        int jb = 4 * (c * 256 + t);
        float4 o;
        o.x = (composite(w.x, jb + 0) >= cutoff) ? w.x : 0.0f;
        o.y = (composite(w.y, jb + 1) >= cutoff) ? w.y : 0.0f;
        o.z = (composite(w.z, jb + 2) >= cutoff) ? w.z : 0.0f;
        o.w = (composite(w.w, jb + 3) >= cutoff) ? w.w : 0.0f;
        ((float4*)rp)[c * 256 + t] = o;
    }
}

extern "C" void kernel_launch(void* const* d_in, const int* in_sizes, int n_in,
                              void* d_out, int out_size, void* d_ws, size_t ws_size,
                              hipStream_t stream) {
    const float* x = (const float*)d_in[0];
    float* out = (float*)d_out;
    float* xn = (float*)d_ws;   // 12.6 MB scratch

    normalize_rows<<<N_ROWS, 256, 0, stream>>>(x, xn);
    gemm_sym<<<NT * (NT + 1) / 2, 256, 0, stream>>>(xn, out);
    topk_mask<<<N_ROWS, 256, 0, stream>>>(out);
}